// Round 1
// baseline (655.594 us; speedup 1.0000x reference)
//
#include <hip/hip_runtime.h>
#include <hip/hip_bf16.h>

#define HW   4096
#define CH   128
#define NCTX 8

using bf16 = __hip_bfloat16;
typedef float f32x4 __attribute__((ext_vector_type(4)));
typedef short s16x8 __attribute__((ext_vector_type(8)));

// ---------------- normalize feat_tar [4096,128] f32 -> bf16 [4096,128] -------
__global__ __launch_bounds__(64) void norm_tar(const float* __restrict__ ft,
                                               bf16* __restrict__ ftn) {
    int t = blockIdx.x;
    int lane = threadIdx.x;
    float2 v = ((const float2*)(ft + (size_t)t * CH))[lane];
    float s = v.x * v.x + v.y * v.y;
    #pragma unroll
    for (int off = 1; off < 64; off <<= 1) s += __shfl_xor(s, off, 64);
    float scale = 1.0f / fmaxf(sqrtf(s), 1e-12f);
    __hip_bfloat162 h;
    h.x = __float2bfloat16(v.x * scale);
    h.y = __float2bfloat16(v.y * scale);
    ((__hip_bfloat162*)(ftn + (size_t)t * CH))[lane] = h;
}

// ------- normalize + transpose feat_refs [8,128,4096] f32 -> bf16 [8,4096,128]
__global__ __launch_bounds__(256) void norm_refs(const float* __restrict__ fr,
                                                 bf16* __restrict__ frt) {
    int idx = blockIdx.x * 256 + threadIdx.x;   // 0..32767 = n*4096 + r
    int n = idx >> 12;
    int r = idx & 4095;
    const float* src = fr + (size_t)n * CH * HW + r;
    float s = 0.f;
    #pragma unroll
    for (int c = 0; c < CH; ++c) {
        float v = src[(size_t)c * HW];
        s += v * v;
    }
    float scale = 1.0f / fmaxf(sqrtf(s), 1e-12f);
    bf16* dst = frt + (size_t)idx * CH;
    #pragma unroll
    for (int c0 = 0; c0 < CH; c0 += 8) {
        union { bf16 h[8]; int4 v; } u;
        #pragma unroll
        for (int j = 0; j < 8; ++j)
            u.h[j] = __float2bfloat16(src[(size_t)(c0 + j) * HW] * scale);
        ((int4*)dst)[c0 / 8] = u.v;
    }
}

// ---------------- fused affinity GEMM + softmax (two passes) -----------------
// A  = ftn [4096][128] bf16 (row-major, K contiguous)
// Bt = frt [8][4096][128] bf16 (r-major, K contiguous)
// C[n][t][r] = sum_c A[t][c] * Bt[n][r][c]
// Pass A (WRITE=false): S[n][t] += sum_r exp(C)   (logits in [-1,1], exp safe)
// Pass B (WRITE=true):  out[n][t][r] = exp(C) / S[n][t]
template <bool WRITE>
__global__ __launch_bounds__(256) void affinity_gemm(
    const bf16* __restrict__ A, const bf16* __restrict__ Bt,
    float* __restrict__ S, float* __restrict__ out) {
    __shared__ bf16 As[128 * 128];
    __shared__ bf16 Bs[128 * 128];

    int n  = blockIdx.z;
    int t0 = blockIdx.y * 128;
    int r0 = blockIdx.x * 128;
    int tid = threadIdx.x;

    // Stage both 128x128 bf16 tiles (32 KB each). Chunk = 8 bf16 = 16 B.
    // XOR-swizzle chunk position by (row & 15) to avoid 16-way LDS bank
    // conflicts on the 256 B row stride during fragment reads.
    const bf16* ga = A + (size_t)t0 * CH;
    const bf16* gb = Bt + ((size_t)n * HW + r0) * CH;
    #pragma unroll
    for (int i = 0; i < 8; ++i) {
        int q = tid + i * 256;          // chunk id 0..2047
        int row = q >> 4, c8 = q & 15;
        int4 va = ((const int4*)(ga + (size_t)row * CH))[c8];
        int4 vb = ((const int4*)(gb + (size_t)row * CH))[c8];
        int sw = c8 ^ (row & 15);
        ((int4*)As)[row * 16 + sw] = va;
        ((int4*)Bs)[row * 16 + sw] = vb;
    }
    __syncthreads();

    int wave = tid >> 6, lane = tid & 63;
    int wm = wave >> 1, wn = wave & 1;      // 2x2 wave grid, 64x64 per wave
    int l15 = lane & 15, quad = lane >> 4;

    f32x4 acc[4][4] = {};
    #pragma unroll
    for (int kc = 0; kc < 4; ++kc) {
        s16x8 af[4], bfr[4];
        #pragma unroll
        for (int i = 0; i < 4; ++i) {
            int arow = wm * 64 + i * 16 + l15;
            int brow = wn * 64 + i * 16 + l15;
            int ch = (kc * 4 + quad) ^ l15;   // row&15 == l15 for both
            af[i]  = ((const s16x8*)As)[arow * 16 + ch];
            bfr[i] = ((const s16x8*)Bs)[brow * 16 + ch];
        }
        #pragma unroll
        for (int mi = 0; mi < 4; ++mi)
            #pragma unroll
            for (int ni = 0; ni < 4; ++ni)
                acc[mi][ni] = __builtin_amdgcn_mfma_f32_16x16x32_bf16(
                    af[mi], bfr[ni], acc[mi][ni], 0, 0, 0);
    }

    // C/D layout (verified m89/m91): col = lane&15, row = quad*4 + reg
    if (!WRITE) {
        #pragma unroll
        for (int mi = 0; mi < 4; ++mi) {
            #pragma unroll
            for (int rg = 0; rg < 4; ++rg) {
                float rs = 0.f;
                #pragma unroll
                for (int ni = 0; ni < 4; ++ni) rs += __expf(acc[mi][ni][rg]);
                #pragma unroll
                for (int off = 1; off < 16; off <<= 1)
                    rs += __shfl_xor(rs, off, 64);
                if (l15 == 0) {
                    int row = t0 + wm * 64 + mi * 16 + quad * 4 + rg;
                    atomicAdd(&S[n * HW + row], rs);
                }
            }
        }
    } else {
        #pragma unroll
        for (int mi = 0; mi < 4; ++mi) {
            #pragma unroll
            for (int rg = 0; rg < 4; ++rg) {
                int row = t0 + wm * 64 + mi * 16 + quad * 4 + rg;
                float inv = 1.0f / S[n * HW + row];
                float* orow = out + ((size_t)n * HW + row) * HW + r0 + wn * 64;
                #pragma unroll
                for (int ni = 0; ni < 4; ++ni)
                    orow[ni * 16 + l15] = __expf(acc[mi][ni][rg]) * inv;
            }
        }
    }
}

extern "C" void kernel_launch(void* const* d_in, const int* in_sizes, int n_in,
                              void* d_out, int out_size, void* d_ws, size_t ws_size,
                              hipStream_t stream) {
    const float* ft = (const float*)d_in[0];   // [4096,128]
    const float* fr = (const float*)d_in[1];   // [8,128,4096]
    float* out = (float*)d_out;                // [8,4096,4096]

    char* ws = (char*)d_ws;
    bf16* ftn = (bf16*)ws;                        // 1 MB
    bf16* frt = (bf16*)(ws + (1 << 20));          // 8 MB
    float* S  = (float*)(ws + (9 << 20));         // 128 KB

    hipMemsetAsync(S, 0, NCTX * HW * sizeof(float), stream);
    norm_tar<<<HW, 64, 0, stream>>>(ft, ftn);
    norm_refs<<<(NCTX * HW) / 256, 256, 0, stream>>>(fr, frt);
    affinity_gemm<false><<<dim3(32, 32, NCTX), 256, 0, stream>>>(ftn, frt, S, out);
    affinity_gemm<true ><<<dim3(32, 32, NCTX), 256, 0, stream>>>(ftn, frt, S, out);
}